// Round 5
// baseline (921.733 us; speedup 1.0000x reference)
//
#include <hip/hip_runtime.h>

// ---------------------------------------------------------------------------
// GCN stack on MI355X.
// R0: S(x@W) == S(x)@W -> aggregate in 64-dim space always; share t1.
// R1: counting-sort CSR + register-accumulating gather (one wave per dst
//     node, lane = feature). Self-term + bias + relu fused into the gather.
// R2: coef folded into CSR (int2 {src,coef}); branch heads merged into one
//     128-wide GEMM + ONE 128-wide gather; epilogues slice via lda=128.
//     Measured 864-900 µs band, absmax 4.9e-4.
// R4 (reverted): big-accumulator GEMM regressed (staging-bound at K=64;
//     occupancy loss exposed barriers).
// R5: templated BK. K=64 GEMMs (Gcat + epilogues) use BK=64: ONE staging
//     round + ONE barrier pair instead of two, all 8 staged float4 loads in
//     flight together. Same 4x4 micro-tile / 16 acc regs. G1 (K=640) keeps
//     the verified BK=32 path. k-summation order unchanged -> bit-identical.
// ---------------------------------------------------------------------------

__global__ void zero_int_kernel(int* __restrict__ p, int n) {
    int i = blockIdx.x * blockDim.x + threadIdx.x;
    if (i < n) p[i] = 0;
}

__global__ void hist_kernel(const int* __restrict__ edges, int* __restrict__ cnt, int E) {
    int e = blockIdx.x * blockDim.x + threadIdx.x;
    if (e < E) atomicAdd(&cnt[edges[2 * e + 1]], 1);
}

// per-block inclusive scan (1024 elems) -> exclusive partial + blocksum; also dinv
__global__ __launch_bounds__(1024)
void scan_block_kernel(const int* __restrict__ cnt, int* __restrict__ excl,
                       int* __restrict__ blocksum, float* __restrict__ dinv, int N) {
    __shared__ int s[1024];
    int tid = threadIdx.x;
    int i = blockIdx.x * 1024 + tid;
    int v = (i < N) ? cnt[i] : 0;
    if (i < N) dinv[i] = rsqrtf((float)v + 1.0f);
    s[tid] = v;
    __syncthreads();
    for (int off = 1; off < 1024; off <<= 1) {
        int t = (tid >= off) ? s[tid - off] : 0;
        __syncthreads();
        s[tid] += t;
        __syncthreads();
    }
    if (i < N) excl[i] = s[tid] - v;
    if (tid == 1023) blocksum[blockIdx.x] = s[1023];
}

__global__ void scan_partials_kernel(int* __restrict__ blocksum, int nb) {
    if (blockIdx.x == 0 && threadIdx.x == 0) {
        int run = 0;
        for (int i = 0; i < nb; ++i) { int v = blocksum[i]; blocksum[i] = run; run += v; }
    }
}

__global__ void scan_finalize_kernel(int* __restrict__ row_start, const int* __restrict__ blocksum,
                                     int* __restrict__ cursor, int N, int E) {
    int i = blockIdx.x * blockDim.x + threadIdx.x;
    if (i < N) {
        int v = row_start[i] + blocksum[i >> 10];
        row_start[i] = v;
        cursor[i] = v;
    }
    if (i == N) row_start[N] = E;
}

// CSR record = {src, coef} with coef = dinv[src]*dinv[dst] pre-folded.
__global__ void build_csr_kernel(const int* __restrict__ edges, int* __restrict__ cursor,
                                 int2* __restrict__ csr, const float* __restrict__ dinv, int E) {
    int e = blockIdx.x * blockDim.x + threadIdx.x;
    if (e < E) {
        int s = edges[2 * e], d = edges[2 * e + 1];
        float c = dinv[s] * dinv[d];
        int pos = atomicAdd(&cursor[d], 1);
        csr[pos] = make_int2(s, __float_as_int(c));
    }
}

// Wcat[k][0:64] = Ws1[k][:]; Wcat[k][64:128] = Ww1[k][:]; bcat likewise.
__global__ void concat_w_kernel(const float* __restrict__ Ws1, const float* __restrict__ Ww1,
                                const float* __restrict__ bs1, const float* __restrict__ bw1,
                                float* __restrict__ Wcat, float* __restrict__ bcat) {
    int i = blockIdx.x * blockDim.x + threadIdx.x;
    if (i < 4096) {
        int k = i >> 6, c = i & 63;
        Wcat[k * 128 + c]       = Ws1[i];
        Wcat[k * 128 + 64 + c]  = Ww1[i];
    }
    if (i < 64) { bcat[i] = bs1[i]; bcat[64 + i] = bw1[i]; }
}

// out[d] = f(in[d])*dinv[d]^2 + sum_{e in row(d)} f(in[src_e]) * coef_e
// one wave per dst node, lane = feature (64 == wave size). No atomics.
template <bool BIAS, bool RELU>
__global__ __launch_bounds__(256)
void agg64_kernel(const float* __restrict__ in, const float* __restrict__ bias,
                  const int* __restrict__ row_start, const int2* __restrict__ csr,
                  const float* __restrict__ dinv, float* __restrict__ out, int N) {
    int lane = threadIdx.x & 63;
    int wid  = (blockIdx.x * blockDim.x + threadIdx.x) >> 6;
    int nw   = (gridDim.x * blockDim.x) >> 6;
    float b = BIAS ? bias[lane] : 0.f;
    for (int d = wid; d < N; d += nw) {
        float dv = dinv[d];
        float v = in[(size_t)d * 64 + lane];
        if (BIAS) v += b;
        if (RELU) v = fmaxf(v, 0.f);
        float acc0 = v * dv * dv;
        float acc1 = 0.f, acc2 = 0.f, acc3 = 0.f;
        int e   = row_start[d];
        int end = row_start[d + 1];
        // 4-way unrolled: four loads in flight, four independent acc chains
        for (; e + 3 < end; e += 4) {
            int2 r0 = csr[e + 0], r1 = csr[e + 1], r2 = csr[e + 2], r3 = csr[e + 3];
            float u0 = in[(size_t)r0.x * 64 + lane];
            float u1 = in[(size_t)r1.x * 64 + lane];
            float u2 = in[(size_t)r2.x * 64 + lane];
            float u3 = in[(size_t)r3.x * 64 + lane];
            if (BIAS) { u0 += b; u1 += b; u2 += b; u3 += b; }
            if (RELU) {
                u0 = fmaxf(u0, 0.f); u1 = fmaxf(u1, 0.f);
                u2 = fmaxf(u2, 0.f); u3 = fmaxf(u3, 0.f);
            }
            acc0 = fmaf(u0, __int_as_float(r0.y), acc0);
            acc1 = fmaf(u1, __int_as_float(r1.y), acc1);
            acc2 = fmaf(u2, __int_as_float(r2.y), acc2);
            acc3 = fmaf(u3, __int_as_float(r3.y), acc3);
        }
        for (; e < end; ++e) {
            int2 r = csr[e];
            float u = in[(size_t)r.x * 64 + lane];
            if (BIAS) u += b;
            if (RELU) u = fmaxf(u, 0.f);
            acc0 = fmaf(u, __int_as_float(r.y), acc0);
        }
        out[(size_t)d * 64 + lane] = (acc0 + acc1) + (acc2 + acc3);
    }
}

// 128-wide variant: lane owns features {2*lane, 2*lane+1} as float2.
// 512B per wave per edge, one traversal for both branches.
__global__ __launch_bounds__(256)
void agg128_kernel(const float* __restrict__ in, const int* __restrict__ row_start,
                   const int2* __restrict__ csr, const float* __restrict__ dinv,
                   float* __restrict__ out, int N) {
    int lane = threadIdx.x & 63;
    int wid  = (blockIdx.x * blockDim.x + threadIdx.x) >> 6;
    int nw   = (gridDim.x * blockDim.x) >> 6;
    for (int d = wid; d < N; d += nw) {
        float dv = dinv[d];
        float2 v = *(const float2*)&in[(size_t)d * 128 + lane * 2];
        float aA = v.x * dv * dv, bA = v.y * dv * dv;
        float aB = 0.f, bB = 0.f;
        int e   = row_start[d];
        int end = row_start[d + 1];
        for (; e + 1 < end; e += 2) {
            int2 r0 = csr[e], r1 = csr[e + 1];
            float2 u0 = *(const float2*)&in[(size_t)r0.x * 128 + lane * 2];
            float2 u1 = *(const float2*)&in[(size_t)r1.x * 128 + lane * 2];
            float c0 = __int_as_float(r0.y), c1 = __int_as_float(r1.y);
            aA = fmaf(u0.x, c0, aA); bA = fmaf(u0.y, c0, bA);
            aB = fmaf(u1.x, c1, aB); bB = fmaf(u1.y, c1, bB);
        }
        if (e < end) {
            int2 r = csr[e];
            float2 u = *(const float2*)&in[(size_t)r.x * 128 + lane * 2];
            float c = __int_as_float(r.y);
            aA = fmaf(u.x, c, aA); bA = fmaf(u.y, c, bA);
        }
        *(float2*)&out[(size_t)d * 128 + lane * 2] = make_float2(aA + aB, bA + bB);
    }
}

// ---------------------------------------------------------------------------
// fp32 GEMM: C[M,N] = A[M,K] @ B[K,N] (+bias) (optional relu)
// tile 64x64, templated BK in {32,64}, 256 threads, 4x4 micro-tile, 16 acc
// regs (occupancy preserved). BK=64 => ONE staging round + barrier pair for
// K=64 calls (they are staging-bound). K must be a multiple of BK.
// lda = A row stride (epilogues read a 64-col slice of a 128-wide buffer).
// ---------------------------------------------------------------------------
template <int BK, bool RELU>
__global__ __launch_bounds__(256)
void gemm_kernel(const float* __restrict__ A, const float* __restrict__ B,
                 const float* __restrict__ bias, float* __restrict__ C,
                 int M, int N, int K, int lda) {
    __shared__ float sA[64][BK + 1];
    __shared__ float sB[BK][64];
    const int tid  = threadIdx.x;
    const int row0 = blockIdx.x * 64;
    const int col0 = blockIdx.y * 64;
    const int tx = tid & 15;
    const int ty = tid >> 4;
    const int tx4 = tx << 2, ty4 = ty << 2;

    float acc[4][4] = {};

    for (int kb = 0; kb < K; kb += BK) {
        // stage A (64 rows x BK k): 16*BK float4s over 256 threads
#pragma unroll
        for (int l = 0; l < BK / 16; ++l) {
            int f  = tid + l * 256;            // 0 .. 16*BK-1
            int r  = f / (BK / 4);             // row 0..63
            int k4 = (f % (BK / 4)) << 2;      // k offset, step 4
            float4 v = make_float4(0.f, 0.f, 0.f, 0.f);
            int gr = row0 + r;
            if (gr < M) v = *(const float4*)&A[(size_t)gr * lda + kb + k4];
            sA[r][k4 + 0] = v.x; sA[r][k4 + 1] = v.y;
            sA[r][k4 + 2] = v.z; sA[r][k4 + 3] = v.w;
        }
        // stage B (BK k-rows x 64 cols): 16*BK float4s over 256 threads
#pragma unroll
        for (int l = 0; l < BK / 16; ++l) {
            int f  = tid + l * 256;
            int kr = f >> 4;                   // 0..BK-1
            int c4 = (f & 15) << 2;            // 0..60
            *(float4*)&sB[kr][c4] = *(const float4*)&B[(size_t)(kb + kr) * N + col0 + c4];
        }
        __syncthreads();
#pragma unroll
        for (int k = 0; k < BK; ++k) {
            float a0 = sA[ty4 + 0][k];
            float a1 = sA[ty4 + 1][k];
            float a2 = sA[ty4 + 2][k];
            float a3 = sA[ty4 + 3][k];
            float4 b = *(const float4*)&sB[k][tx4];
            acc[0][0] = fmaf(a0, b.x, acc[0][0]); acc[0][1] = fmaf(a0, b.y, acc[0][1]);
            acc[0][2] = fmaf(a0, b.z, acc[0][2]); acc[0][3] = fmaf(a0, b.w, acc[0][3]);
            acc[1][0] = fmaf(a1, b.x, acc[1][0]); acc[1][1] = fmaf(a1, b.y, acc[1][1]);
            acc[1][2] = fmaf(a1, b.z, acc[1][2]); acc[1][3] = fmaf(a1, b.w, acc[1][3]);
            acc[2][0] = fmaf(a2, b.x, acc[2][0]); acc[2][1] = fmaf(a2, b.y, acc[2][1]);
            acc[2][2] = fmaf(a2, b.z, acc[2][2]); acc[2][3] = fmaf(a2, b.w, acc[2][3]);
            acc[3][0] = fmaf(a3, b.x, acc[3][0]); acc[3][1] = fmaf(a3, b.y, acc[3][1]);
            acc[3][2] = fmaf(a3, b.z, acc[3][2]); acc[3][3] = fmaf(a3, b.w, acc[3][3]);
        }
        __syncthreads();
    }

    float4 bv = make_float4(0.f, 0.f, 0.f, 0.f);
    if (bias) bv = *(const float4*)&bias[col0 + tx4];
#pragma unroll
    for (int i = 0; i < 4; ++i) {
        int gr = row0 + ty4 + i;
        if (gr < M) {
            float4 v;
            v.x = acc[i][0] + bv.x; v.y = acc[i][1] + bv.y;
            v.z = acc[i][2] + bv.z; v.w = acc[i][3] + bv.w;
            if (RELU) {
                v.x = fmaxf(v.x, 0.f); v.y = fmaxf(v.y, 0.f);
                v.z = fmaxf(v.z, 0.f); v.w = fmaxf(v.w, 0.f);
            }
            *(float4*)&C[(size_t)gr * N + col0 + tx4] = v;
        }
    }
}

extern "C" void kernel_launch(void* const* d_in, const int* in_sizes, int n_in,
                              void* d_out, int out_size, void* d_ws, size_t ws_size,
                              hipStream_t stream) {
    const float* x     = (const float*)d_in[0];
    const int*   edges = (const int*)d_in[1];
    const float* Wb    = (const float*)d_in[2];
    const float* bb    = (const float*)d_in[3];
    const float* Ws1   = (const float*)d_in[4];
    const float* bs1   = (const float*)d_in[5];
    const float* Ws2   = (const float*)d_in[6];
    const float* bs2   = (const float*)d_in[7];
    const float* Ww1   = (const float*)d_in[8];
    const float* bw1   = (const float*)d_in[9];
    const float* Ww2   = (const float*)d_in[10];
    const float* bw2   = (const float*)d_in[11];

    const int N = in_sizes[0] / 640;   // 50000
    const int E = in_sizes[1] / 2;     // 1600000

    float* out_xs = (float*)d_out;
    float* out_xw = out_xs + (size_t)N * 640;

    // workspace layout (all 256B-aligned)
    const size_t NP = ((size_t)N + 64) & ~63ULL;   // padded count
    char* w = (char*)d_ws;
    float* dinv      = (float*)w;              w += NP * 4;
    int*   cnt       = (int*)w;                w += NP * 4;
    int*   row_start = (int*)w;                w += (NP + 64) * 4;
    int*   cursor    = (int*)w;                w += NP * 4;
    int2*  csr       = (int2*)w;               w += ((size_t)E + 64) * 8;
    float* Wcat      = (float*)w;              w += 8192 * 4;
    float* bcat      = (float*)w;              w += 256 * 4;
    size_t nf = (size_t)N * 64;
    float* B0 = (float*)w;                     w += nf * 4;
    float* B1 = (float*)w;                     w += nf * 4;
    float* B2 = (float*)w;                     w += nf * 4;
    float* Bcat = (float*)w;                   w += (size_t)N * 128 * 4;  // pre-agg 128-wide
    float* B128 = (float*)w;                   w += (size_t)N * 128 * 4;  // post-agg 128-wide

    const dim3 blk(256);
    const int nBlkN   = (N + 255) / 256;
    const int nBlkN1  = (N + 256) / 256;       // covers i == N
    const int nBlkE   = (E + 255) / 256;
    const int nScanB  = (N + 1023) / 1024;
    const int rowT    = (N + 63) / 64;
    const int gatherB = (N + 3) / 4;           // 4 waves per block, 1 wave/node

    // --- CSR build + dinv (coef folded into CSR record) ---
    zero_int_kernel<<<nBlkN, blk, 0, stream>>>(cnt, N);
    hist_kernel<<<nBlkE, blk, 0, stream>>>(edges, cnt, E);
    scan_block_kernel<<<nScanB, 1024, 0, stream>>>(cnt, row_start, cursor /*tmp blocksum*/, dinv, N);
    scan_partials_kernel<<<1, 64, 0, stream>>>(cursor, nScanB);
    scan_finalize_kernel<<<nBlkN1, blk, 0, stream>>>(row_start, cursor, cnt /*reuse as cursor*/, N, E);
    build_csr_kernel<<<nBlkE, blk, 0, stream>>>(edges, cnt, csr, dinv, E);

    // --- concat [Ws1|Ww1], [bs1|bw1] (tiny) ---
    concat_w_kernel<<<16, blk, 0, stream>>>(Ws1, Ww1, bs1, bw1, Wcat, bcat);

    // --- G1: hb = x @ Wb (K=640: BK=32 pipelined path, verified) ---
    gemm_kernel<32, false><<<dim3(rowT, 1), blk, 0, stream>>>(x, Wb, nullptr, B0, N, 64, 640, 640);

    // --- A1: ab = S(hb) ---
    agg64_kernel<false, false><<<gatherB, blk, 0, stream>>>(B0, nullptr, row_start, csr, dinv, B1, N);

    // --- A2: t1 = S(relu(ab + bb)) ---
    agg64_kernel<true, true><<<gatherB, blk, 0, stream>>>(B1, bb, row_start, csr, dinv, B2, N);

    // --- merged branch heads: Bcat = relu(t1 @ [Ws1|Ww1] + [bs1|bw1]) (K=64: one-shot BK=64) ---
    gemm_kernel<64, true><<<dim3(rowT, 2), blk, 0, stream>>>(B2, Wcat, bcat, Bcat, N, 128, 64, 64);

    // --- A3+A4 merged: B128 = S(Bcat), one traversal for both branches ---
    agg128_kernel<<<gatherB, blk, 0, stream>>>(Bcat, row_start, csr, dinv, B128, N);

    // --- epilogues: slice the two halves via lda=128 (K=64: one-shot BK=64) ---
    gemm_kernel<64, true><<<dim3(rowT, 10), blk, 0, stream>>>(B128,      Ws2, bs2, out_xs, N, 640, 64, 128);
    gemm_kernel<64, true><<<dim3(rowT, 10), blk, 0, stream>>>(B128 + 64, Ww2, bw2, out_xw, N, 640, 64, 128);
}

// Round 6
// 901.570 us; speedup vs baseline: 1.0224x; 1.0224x over previous
//
#include <hip/hip_runtime.h>

// ---------------------------------------------------------------------------
// GCN stack on MI355X.  FINAL: best measured config (R2, 864.4 µs).
// R0: S(x@W) == S(x)@W -> aggregate in 64-dim space always; share t1.
// R1: counting-sort CSR + register-accumulating gather (one wave per dst
//     node, lane = feature). Self-term + bias + relu fused into the gather.
// R2: coef folded into CSR (int2 {src,coef}); branch heads merged into one
//     128-wide GEMM + ONE 128-wide gather; epilogues slice via lda=128.
//     Measured 864.4 / 895.6 / 900.2 µs, absmax 4.9e-4.
// R4 (reverted, 947 µs): TM=128 / 8x8 micro-tile GEMM — VGPR growth halved
//     occupancy; K=64 GEMMs are staging-bound, occupancy hides the barriers.
// R5 (reverted, 922 µs): BK=64 one-shot staging — LDS growth (33 KB) halved
//     blocks/CU; same lesson from the LDS side.
// Structural note for future work: the 3 K=64 GEMMs (~260 µs total) sit ~4x
// above their write-BW floor but resist per-block resource increases; the
// path forward is split-K or MFMA/bf16, both requiring verification cycles.
// ---------------------------------------------------------------------------

__global__ void zero_int_kernel(int* __restrict__ p, int n) {
    int i = blockIdx.x * blockDim.x + threadIdx.x;
    if (i < n) p[i] = 0;
}

__global__ void hist_kernel(const int* __restrict__ edges, int* __restrict__ cnt, int E) {
    int e = blockIdx.x * blockDim.x + threadIdx.x;
    if (e < E) atomicAdd(&cnt[edges[2 * e + 1]], 1);
}

// per-block inclusive scan (1024 elems) -> exclusive partial + blocksum; also dinv
__global__ __launch_bounds__(1024)
void scan_block_kernel(const int* __restrict__ cnt, int* __restrict__ excl,
                       int* __restrict__ blocksum, float* __restrict__ dinv, int N) {
    __shared__ int s[1024];
    int tid = threadIdx.x;
    int i = blockIdx.x * 1024 + tid;
    int v = (i < N) ? cnt[i] : 0;
    if (i < N) dinv[i] = rsqrtf((float)v + 1.0f);
    s[tid] = v;
    __syncthreads();
    for (int off = 1; off < 1024; off <<= 1) {
        int t = (tid >= off) ? s[tid - off] : 0;
        __syncthreads();
        s[tid] += t;
        __syncthreads();
    }
    if (i < N) excl[i] = s[tid] - v;
    if (tid == 1023) blocksum[blockIdx.x] = s[1023];
}

__global__ void scan_partials_kernel(int* __restrict__ blocksum, int nb) {
    if (blockIdx.x == 0 && threadIdx.x == 0) {
        int run = 0;
        for (int i = 0; i < nb; ++i) { int v = blocksum[i]; blocksum[i] = run; run += v; }
    }
}

__global__ void scan_finalize_kernel(int* __restrict__ row_start, const int* __restrict__ blocksum,
                                     int* __restrict__ cursor, int N, int E) {
    int i = blockIdx.x * blockDim.x + threadIdx.x;
    if (i < N) {
        int v = row_start[i] + blocksum[i >> 10];
        row_start[i] = v;
        cursor[i] = v;
    }
    if (i == N) row_start[N] = E;
}

// CSR record = {src, coef} with coef = dinv[src]*dinv[dst] pre-folded.
__global__ void build_csr_kernel(const int* __restrict__ edges, int* __restrict__ cursor,
                                 int2* __restrict__ csr, const float* __restrict__ dinv, int E) {
    int e = blockIdx.x * blockDim.x + threadIdx.x;
    if (e < E) {
        int s = edges[2 * e], d = edges[2 * e + 1];
        float c = dinv[s] * dinv[d];
        int pos = atomicAdd(&cursor[d], 1);
        csr[pos] = make_int2(s, __float_as_int(c));
    }
}

// Wcat[k][0:64] = Ws1[k][:]; Wcat[k][64:128] = Ww1[k][:]; bcat likewise.
__global__ void concat_w_kernel(const float* __restrict__ Ws1, const float* __restrict__ Ww1,
                                const float* __restrict__ bs1, const float* __restrict__ bw1,
                                float* __restrict__ Wcat, float* __restrict__ bcat) {
    int i = blockIdx.x * blockDim.x + threadIdx.x;
    if (i < 4096) {
        int k = i >> 6, c = i & 63;
        Wcat[k * 128 + c]       = Ws1[i];
        Wcat[k * 128 + 64 + c]  = Ww1[i];
    }
    if (i < 64) { bcat[i] = bs1[i]; bcat[64 + i] = bw1[i]; }
}

// out[d] = f(in[d])*dinv[d]^2 + sum_{e in row(d)} f(in[src_e]) * coef_e
// one wave per dst node, lane = feature (64 == wave size). No atomics.
template <bool BIAS, bool RELU>
__global__ __launch_bounds__(256)
void agg64_kernel(const float* __restrict__ in, const float* __restrict__ bias,
                  const int* __restrict__ row_start, const int2* __restrict__ csr,
                  const float* __restrict__ dinv, float* __restrict__ out, int N) {
    int lane = threadIdx.x & 63;
    int wid  = (blockIdx.x * blockDim.x + threadIdx.x) >> 6;
    int nw   = (gridDim.x * blockDim.x) >> 6;
    float b = BIAS ? bias[lane] : 0.f;
    for (int d = wid; d < N; d += nw) {
        float dv = dinv[d];
        float v = in[(size_t)d * 64 + lane];
        if (BIAS) v += b;
        if (RELU) v = fmaxf(v, 0.f);
        float acc0 = v * dv * dv;
        float acc1 = 0.f, acc2 = 0.f, acc3 = 0.f;
        int e   = row_start[d];
        int end = row_start[d + 1];
        // 4-way unrolled: four loads in flight, four independent acc chains
        for (; e + 3 < end; e += 4) {
            int2 r0 = csr[e + 0], r1 = csr[e + 1], r2 = csr[e + 2], r3 = csr[e + 3];
            float u0 = in[(size_t)r0.x * 64 + lane];
            float u1 = in[(size_t)r1.x * 64 + lane];
            float u2 = in[(size_t)r2.x * 64 + lane];
            float u3 = in[(size_t)r3.x * 64 + lane];
            if (BIAS) { u0 += b; u1 += b; u2 += b; u3 += b; }
            if (RELU) {
                u0 = fmaxf(u0, 0.f); u1 = fmaxf(u1, 0.f);
                u2 = fmaxf(u2, 0.f); u3 = fmaxf(u3, 0.f);
            }
            acc0 = fmaf(u0, __int_as_float(r0.y), acc0);
            acc1 = fmaf(u1, __int_as_float(r1.y), acc1);
            acc2 = fmaf(u2, __int_as_float(r2.y), acc2);
            acc3 = fmaf(u3, __int_as_float(r3.y), acc3);
        }
        for (; e < end; ++e) {
            int2 r = csr[e];
            float u = in[(size_t)r.x * 64 + lane];
            if (BIAS) u += b;
            if (RELU) u = fmaxf(u, 0.f);
            acc0 = fmaf(u, __int_as_float(r.y), acc0);
        }
        out[(size_t)d * 64 + lane] = (acc0 + acc1) + (acc2 + acc3);
    }
}

// 128-wide variant: lane owns features {2*lane, 2*lane+1} as float2.
// 512B per wave per edge, one traversal for both branches.
__global__ __launch_bounds__(256)
void agg128_kernel(const float* __restrict__ in, const int* __restrict__ row_start,
                   const int2* __restrict__ csr, const float* __restrict__ dinv,
                   float* __restrict__ out, int N) {
    int lane = threadIdx.x & 63;
    int wid  = (blockIdx.x * blockDim.x + threadIdx.x) >> 6;
    int nw   = (gridDim.x * blockDim.x) >> 6;
    for (int d = wid; d < N; d += nw) {
        float dv = dinv[d];
        float2 v = *(const float2*)&in[(size_t)d * 128 + lane * 2];
        float aA = v.x * dv * dv, bA = v.y * dv * dv;
        float aB = 0.f, bB = 0.f;
        int e   = row_start[d];
        int end = row_start[d + 1];
        for (; e + 1 < end; e += 2) {
            int2 r0 = csr[e], r1 = csr[e + 1];
            float2 u0 = *(const float2*)&in[(size_t)r0.x * 128 + lane * 2];
            float2 u1 = *(const float2*)&in[(size_t)r1.x * 128 + lane * 2];
            float c0 = __int_as_float(r0.y), c1 = __int_as_float(r1.y);
            aA = fmaf(u0.x, c0, aA); bA = fmaf(u0.y, c0, bA);
            aB = fmaf(u1.x, c1, aB); bB = fmaf(u1.y, c1, bB);
        }
        if (e < end) {
            int2 r = csr[e];
            float2 u = *(const float2*)&in[(size_t)r.x * 128 + lane * 2];
            float c = __int_as_float(r.y);
            aA = fmaf(u.x, c, aA); bA = fmaf(u.y, c, bA);
        }
        *(float2*)&out[(size_t)d * 128 + lane * 2] = make_float2(aA + aB, bA + bB);
    }
}

// ---------------------------------------------------------------------------
// fp32 GEMM: C[M,N] = A[M,K] @ B[K,N] (+bias) (optional relu)
// tile 64x64, BK=32, 256 threads, 4x4 micro-tile per thread. 68 VGPRs,
// 12.7 KB LDS -> high occupancy, which is what hides the staging barriers
// at K=64 (verified: VGPR growth (R4) and LDS growth (R5) both regressed).
// lda = A row stride (epilogues read a 64-col slice of a 128-wide buffer).
// ---------------------------------------------------------------------------
template <bool RELU>
__global__ __launch_bounds__(256)
void gemm_kernel(const float* __restrict__ A, const float* __restrict__ B,
                 const float* __restrict__ bias, float* __restrict__ C,
                 int M, int N, int K, int lda) {
    __shared__ float sA[64][33];
    __shared__ float sB[32][64];
    const int tid  = threadIdx.x;
    const int row0 = blockIdx.x * 64;
    const int col0 = blockIdx.y * 64;
    const int tx = tid & 15;
    const int ty = tid >> 4;
    const int tx4 = tx << 2, ty4 = ty << 2;

    float acc[4][4] = {};

    for (int kb = 0; kb < K; kb += 32) {
#pragma unroll
        for (int l = 0; l < 2; ++l) {
            int f  = tid + l * 256;
            int r  = f >> 3;
            int k4 = (f & 7) << 2;
            float4 v = make_float4(0.f, 0.f, 0.f, 0.f);
            int gr = row0 + r;
            if (gr < M) v = *(const float4*)&A[(size_t)gr * lda + kb + k4];
            sA[r][k4 + 0] = v.x; sA[r][k4 + 1] = v.y;
            sA[r][k4 + 2] = v.z; sA[r][k4 + 3] = v.w;
        }
#pragma unroll
        for (int l = 0; l < 2; ++l) {
            int f  = tid + l * 256;
            int kr = f >> 4;
            int c4 = (f & 15) << 2;
            *(float4*)&sB[kr][c4] = *(const float4*)&B[(size_t)(kb + kr) * N + col0 + c4];
        }
        __syncthreads();
#pragma unroll
        for (int k = 0; k < 32; ++k) {
            float a0 = sA[ty4 + 0][k];
            float a1 = sA[ty4 + 1][k];
            float a2 = sA[ty4 + 2][k];
            float a3 = sA[ty4 + 3][k];
            float4 b = *(const float4*)&sB[k][tx4];
            acc[0][0] = fmaf(a0, b.x, acc[0][0]); acc[0][1] = fmaf(a0, b.y, acc[0][1]);
            acc[0][2] = fmaf(a0, b.z, acc[0][2]); acc[0][3] = fmaf(a0, b.w, acc[0][3]);
            acc[1][0] = fmaf(a1, b.x, acc[1][0]); acc[1][1] = fmaf(a1, b.y, acc[1][1]);
            acc[1][2] = fmaf(a1, b.z, acc[1][2]); acc[1][3] = fmaf(a1, b.w, acc[1][3]);
            acc[2][0] = fmaf(a2, b.x, acc[2][0]); acc[2][1] = fmaf(a2, b.y, acc[2][1]);
            acc[2][2] = fmaf(a2, b.z, acc[2][2]); acc[2][3] = fmaf(a2, b.w, acc[2][3]);
            acc[3][0] = fmaf(a3, b.x, acc[3][0]); acc[3][1] = fmaf(a3, b.y, acc[3][1]);
            acc[3][2] = fmaf(a3, b.z, acc[3][2]); acc[3][3] = fmaf(a3, b.w, acc[3][3]);
        }
        __syncthreads();
    }

    float4 bv = make_float4(0.f, 0.f, 0.f, 0.f);
    if (bias) bv = *(const float4*)&bias[col0 + tx4];
#pragma unroll
    for (int i = 0; i < 4; ++i) {
        int gr = row0 + ty4 + i;
        if (gr < M) {
            float4 v;
            v.x = acc[i][0] + bv.x; v.y = acc[i][1] + bv.y;
            v.z = acc[i][2] + bv.z; v.w = acc[i][3] + bv.w;
            if (RELU) {
                v.x = fmaxf(v.x, 0.f); v.y = fmaxf(v.y, 0.f);
                v.z = fmaxf(v.z, 0.f); v.w = fmaxf(v.w, 0.f);
            }
            *(float4*)&C[(size_t)gr * N + col0 + tx4] = v;
        }
    }
}

extern "C" void kernel_launch(void* const* d_in, const int* in_sizes, int n_in,
                              void* d_out, int out_size, void* d_ws, size_t ws_size,
                              hipStream_t stream) {
    const float* x     = (const float*)d_in[0];
    const int*   edges = (const int*)d_in[1];
    const float* Wb    = (const float*)d_in[2];
    const float* bb    = (const float*)d_in[3];
    const float* Ws1   = (const float*)d_in[4];
    const float* bs1   = (const float*)d_in[5];
    const float* Ws2   = (const float*)d_in[6];
    const float* bs2   = (const float*)d_in[7];
    const float* Ww1   = (const float*)d_in[8];
    const float* bw1   = (const float*)d_in[9];
    const float* Ww2   = (const float*)d_in[10];
    const float* bw2   = (const float*)d_in[11];

    const int N = in_sizes[0] / 640;   // 50000
    const int E = in_sizes[1] / 2;     // 1600000

    float* out_xs = (float*)d_out;
    float* out_xw = out_xs + (size_t)N * 640;

    // workspace layout (all 256B-aligned)
    const size_t NP = ((size_t)N + 64) & ~63ULL;   // padded count
    char* w = (char*)d_ws;
    float* dinv      = (float*)w;              w += NP * 4;
    int*   cnt       = (int*)w;                w += NP * 4;
    int*   row_start = (int*)w;                w += (NP + 64) * 4;
    int*   cursor    = (int*)w;                w += NP * 4;
    int2*  csr       = (int2*)w;               w += ((size_t)E + 64) * 8;
    float* Wcat      = (float*)w;              w += 8192 * 4;
    float* bcat      = (float*)w;              w += 256 * 4;
    size_t nf = (size_t)N * 64;
    float* B0 = (float*)w;                     w += nf * 4;
    float* B1 = (float*)w;                     w += nf * 4;
    float* B2 = (float*)w;                     w += nf * 4;
    float* Bcat = (float*)w;                   w += (size_t)N * 128 * 4;  // pre-agg 128-wide
    float* B128 = (float*)w;                   w += (size_t)N * 128 * 4;  // post-agg 128-wide

    const dim3 blk(256);
    const int nBlkN   = (N + 255) / 256;
    const int nBlkN1  = (N + 256) / 256;       // covers i == N
    const int nBlkE   = (E + 255) / 256;
    const int nScanB  = (N + 1023) / 1024;
    const int rowT    = (N + 63) / 64;
    const int gatherB = (N + 3) / 4;           // 4 waves per block, 1 wave/node

    // --- CSR build + dinv (coef folded into CSR record) ---
    zero_int_kernel<<<nBlkN, blk, 0, stream>>>(cnt, N);
    hist_kernel<<<nBlkE, blk, 0, stream>>>(edges, cnt, E);
    scan_block_kernel<<<nScanB, 1024, 0, stream>>>(cnt, row_start, cursor /*tmp blocksum*/, dinv, N);
    scan_partials_kernel<<<1, 64, 0, stream>>>(cursor, nScanB);
    scan_finalize_kernel<<<nBlkN1, blk, 0, stream>>>(row_start, cursor, cnt /*reuse as cursor*/, N, E);
    build_csr_kernel<<<nBlkE, blk, 0, stream>>>(edges, cnt, csr, dinv, E);

    // --- concat [Ws1|Ww1], [bs1|bw1] (tiny) ---
    concat_w_kernel<<<16, blk, 0, stream>>>(Ws1, Ww1, bs1, bw1, Wcat, bcat);

    // --- G1: hb = x @ Wb (bias folded into A2's read transform) ---
    gemm_kernel<false><<<dim3(rowT, 1), blk, 0, stream>>>(x, Wb, nullptr, B0, N, 64, 640, 640);

    // --- A1: ab = S(hb) ---
    agg64_kernel<false, false><<<gatherB, blk, 0, stream>>>(B0, nullptr, row_start, csr, dinv, B1, N);

    // --- A2: t1 = S(relu(ab + bb)) ---
    agg64_kernel<true, true><<<gatherB, blk, 0, stream>>>(B1, bb, row_start, csr, dinv, B2, N);

    // --- merged branch heads: Bcat = relu(t1 @ [Ws1|Ww1] + [bs1|bw1]) ---
    gemm_kernel<true><<<dim3(rowT, 2), blk, 0, stream>>>(B2, Wcat, bcat, Bcat, N, 128, 64, 64);

    // --- A3+A4 merged: B128 = S(Bcat), one traversal for both branches ---
    agg128_kernel<<<gatherB, blk, 0, stream>>>(Bcat, row_start, csr, dinv, B128, N);

    // --- epilogues: slice the two halves via lda=128 ---
    gemm_kernel<true><<<dim3(rowT, 10), blk, 0, stream>>>(B128,      Ws2, bs2, out_xs, N, 640, 64, 128);
    gemm_kernel<true><<<dim3(rowT, 10), blk, 0, stream>>>(B128 + 64, Ww2, bw2, out_xw, N, 640, 64, 128);
}

// Round 7
// 886.085 us; speedup vs baseline: 1.0402x; 1.0175x over previous
//
#include <hip/hip_runtime.h>

// ---------------------------------------------------------------------------
// GCN stack on MI355X.
// R0: S(x@W) == S(x)@W -> aggregate in 64-dim space always; share t1.
// R1: counting-sort CSR + register-accumulating gather (one wave per dst
//     node, lane = feature). Self-term + bias + relu fused into the gather.
// R2: coef folded into CSR (int2 {src,coef}); branch heads merged into one
//     128-wide GEMM + ONE 128-wide gather; epilogues slice via lda=128.
//     Measured 864.4 / 895.6 / 900.2 / 901.6 µs, absmax 4.9e-4.
// R4 (reverted, 947 µs): TM=128 / 8x8 micro-tile — VGPR growth halved
//     occupancy; K=64 GEMMs are staging-bound, occupancy hides barriers.
// R5 (reverted, 922 µs): BK=64 one-shot staging — LDS 33 KB halved blocks/CU.
// R7: k-major sA (sA[k][m], stride 68 = 16B-aligned). The 4 scalar A-reads
//     per k-step become ONE ds_read_b128; inner loop 16 FMA + 2 LDS ops
//     (was 16 FMA + 5). Tile/VGPR/acc unchanged; LDS 12.7->16.9 KB stays
//     under the 8-blocks/CU wave cap -> occupancy IDENTICAL. Staging writes
//     same 4 scalar ds_writes (transposed). Bit-identical k-order.
// ---------------------------------------------------------------------------

__global__ void zero_int_kernel(int* __restrict__ p, int n) {
    int i = blockIdx.x * blockDim.x + threadIdx.x;
    if (i < n) p[i] = 0;
}

__global__ void hist_kernel(const int* __restrict__ edges, int* __restrict__ cnt, int E) {
    int e = blockIdx.x * blockDim.x + threadIdx.x;
    if (e < E) atomicAdd(&cnt[edges[2 * e + 1]], 1);
}

// per-block inclusive scan (1024 elems) -> exclusive partial + blocksum; also dinv
__global__ __launch_bounds__(1024)
void scan_block_kernel(const int* __restrict__ cnt, int* __restrict__ excl,
                       int* __restrict__ blocksum, float* __restrict__ dinv, int N) {
    __shared__ int s[1024];
    int tid = threadIdx.x;
    int i = blockIdx.x * 1024 + tid;
    int v = (i < N) ? cnt[i] : 0;
    if (i < N) dinv[i] = rsqrtf((float)v + 1.0f);
    s[tid] = v;
    __syncthreads();
    for (int off = 1; off < 1024; off <<= 1) {
        int t = (tid >= off) ? s[tid - off] : 0;
        __syncthreads();
        s[tid] += t;
        __syncthreads();
    }
    if (i < N) excl[i] = s[tid] - v;
    if (tid == 1023) blocksum[blockIdx.x] = s[1023];
}

__global__ void scan_partials_kernel(int* __restrict__ blocksum, int nb) {
    if (blockIdx.x == 0 && threadIdx.x == 0) {
        int run = 0;
        for (int i = 0; i < nb; ++i) { int v = blocksum[i]; blocksum[i] = run; run += v; }
    }
}

__global__ void scan_finalize_kernel(int* __restrict__ row_start, const int* __restrict__ blocksum,
                                     int* __restrict__ cursor, int N, int E) {
    int i = blockIdx.x * blockDim.x + threadIdx.x;
    if (i < N) {
        int v = row_start[i] + blocksum[i >> 10];
        row_start[i] = v;
        cursor[i] = v;
    }
    if (i == N) row_start[N] = E;
}

// CSR record = {src, coef} with coef = dinv[src]*dinv[dst] pre-folded.
__global__ void build_csr_kernel(const int* __restrict__ edges, int* __restrict__ cursor,
                                 int2* __restrict__ csr, const float* __restrict__ dinv, int E) {
    int e = blockIdx.x * blockDim.x + threadIdx.x;
    if (e < E) {
        int s = edges[2 * e], d = edges[2 * e + 1];
        float c = dinv[s] * dinv[d];
        int pos = atomicAdd(&cursor[d], 1);
        csr[pos] = make_int2(s, __float_as_int(c));
    }
}

// Wcat[k][0:64] = Ws1[k][:]; Wcat[k][64:128] = Ww1[k][:]; bcat likewise.
__global__ void concat_w_kernel(const float* __restrict__ Ws1, const float* __restrict__ Ww1,
                                const float* __restrict__ bs1, const float* __restrict__ bw1,
                                float* __restrict__ Wcat, float* __restrict__ bcat) {
    int i = blockIdx.x * blockDim.x + threadIdx.x;
    if (i < 4096) {
        int k = i >> 6, c = i & 63;
        Wcat[k * 128 + c]       = Ws1[i];
        Wcat[k * 128 + 64 + c]  = Ww1[i];
    }
    if (i < 64) { bcat[i] = bs1[i]; bcat[64 + i] = bw1[i]; }
}

// out[d] = f(in[d])*dinv[d]^2 + sum_{e in row(d)} f(in[src_e]) * coef_e
// one wave per dst node, lane = feature (64 == wave size). No atomics.
template <bool BIAS, bool RELU>
__global__ __launch_bounds__(256)
void agg64_kernel(const float* __restrict__ in, const float* __restrict__ bias,
                  const int* __restrict__ row_start, const int2* __restrict__ csr,
                  const float* __restrict__ dinv, float* __restrict__ out, int N) {
    int lane = threadIdx.x & 63;
    int wid  = (blockIdx.x * blockDim.x + threadIdx.x) >> 6;
    int nw   = (gridDim.x * blockDim.x) >> 6;
    float b = BIAS ? bias[lane] : 0.f;
    for (int d = wid; d < N; d += nw) {
        float dv = dinv[d];
        float v = in[(size_t)d * 64 + lane];
        if (BIAS) v += b;
        if (RELU) v = fmaxf(v, 0.f);
        float acc0 = v * dv * dv;
        float acc1 = 0.f, acc2 = 0.f, acc3 = 0.f;
        int e   = row_start[d];
        int end = row_start[d + 1];
        // 4-way unrolled: four loads in flight, four independent acc chains
        for (; e + 3 < end; e += 4) {
            int2 r0 = csr[e + 0], r1 = csr[e + 1], r2 = csr[e + 2], r3 = csr[e + 3];
            float u0 = in[(size_t)r0.x * 64 + lane];
            float u1 = in[(size_t)r1.x * 64 + lane];
            float u2 = in[(size_t)r2.x * 64 + lane];
            float u3 = in[(size_t)r3.x * 64 + lane];
            if (BIAS) { u0 += b; u1 += b; u2 += b; u3 += b; }
            if (RELU) {
                u0 = fmaxf(u0, 0.f); u1 = fmaxf(u1, 0.f);
                u2 = fmaxf(u2, 0.f); u3 = fmaxf(u3, 0.f);
            }
            acc0 = fmaf(u0, __int_as_float(r0.y), acc0);
            acc1 = fmaf(u1, __int_as_float(r1.y), acc1);
            acc2 = fmaf(u2, __int_as_float(r2.y), acc2);
            acc3 = fmaf(u3, __int_as_float(r3.y), acc3);
        }
        for (; e < end; ++e) {
            int2 r = csr[e];
            float u = in[(size_t)r.x * 64 + lane];
            if (BIAS) u += b;
            if (RELU) u = fmaxf(u, 0.f);
            acc0 = fmaf(u, __int_as_float(r.y), acc0);
        }
        out[(size_t)d * 64 + lane] = (acc0 + acc1) + (acc2 + acc3);
    }
}

// 128-wide variant: lane owns features {2*lane, 2*lane+1} as float2.
// 512B per wave per edge, one traversal for both branches.
__global__ __launch_bounds__(256)
void agg128_kernel(const float* __restrict__ in, const int* __restrict__ row_start,
                   const int2* __restrict__ csr, const float* __restrict__ dinv,
                   float* __restrict__ out, int N) {
    int lane = threadIdx.x & 63;
    int wid  = (blockIdx.x * blockDim.x + threadIdx.x) >> 6;
    int nw   = (gridDim.x * blockDim.x) >> 6;
    for (int d = wid; d < N; d += nw) {
        float dv = dinv[d];
        float2 v = *(const float2*)&in[(size_t)d * 128 + lane * 2];
        float aA = v.x * dv * dv, bA = v.y * dv * dv;
        float aB = 0.f, bB = 0.f;
        int e   = row_start[d];
        int end = row_start[d + 1];
        for (; e + 1 < end; e += 2) {
            int2 r0 = csr[e], r1 = csr[e + 1];
            float2 u0 = *(const float2*)&in[(size_t)r0.x * 128 + lane * 2];
            float2 u1 = *(const float2*)&in[(size_t)r1.x * 128 + lane * 2];
            float c0 = __int_as_float(r0.y), c1 = __int_as_float(r1.y);
            aA = fmaf(u0.x, c0, aA); bA = fmaf(u0.y, c0, bA);
            aB = fmaf(u1.x, c1, aB); bB = fmaf(u1.y, c1, bB);
        }
        if (e < end) {
            int2 r = csr[e];
            float2 u = *(const float2*)&in[(size_t)r.x * 128 + lane * 2];
            float c = __int_as_float(r.y);
            aA = fmaf(u.x, c, aA); bA = fmaf(u.y, c, bA);
        }
        *(float2*)&out[(size_t)d * 128 + lane * 2] = make_float2(aA + aB, bA + bB);
    }
}

// ---------------------------------------------------------------------------
// fp32 GEMM: C[M,N] = A[M,K] @ B[K,N] (+bias) (optional relu)
// tile 64x64, BK=32, 256 threads, 4x4 micro-tile per thread.
// sA stored k-major [k][m] with stride 68 (=17*16B, so float4 reads at
// sA[k][ty4] are 16B-aligned). Inner loop: 1 ds_read_b128 (A) + 1 (B) +
// 16 FMA per k-step. LDS 16.9 KB — still >= 8 blocks/CU (wave-capped),
// occupancy identical to the verified R2 kernel. 16 acc regs.
// lda = A row stride (epilogues read a 64-col slice of a 128-wide buffer).
// ---------------------------------------------------------------------------
template <bool RELU>
__global__ __launch_bounds__(256)
void gemm_kernel(const float* __restrict__ A, const float* __restrict__ B,
                 const float* __restrict__ bias, float* __restrict__ C,
                 int M, int N, int K, int lda) {
    __shared__ float sA[32][68];   // [k][m], stride 68 floats = 272 B (16B-aligned rows)
    __shared__ float sB[32][64];
    const int tid  = threadIdx.x;
    const int row0 = blockIdx.x * 64;
    const int col0 = blockIdx.y * 64;
    const int tx = tid & 15;
    const int ty = tid >> 4;
    const int tx4 = tx << 2, ty4 = ty << 2;

    float acc[4][4] = {};

    for (int kb = 0; kb < K; kb += 32) {
        // stage A (64 rows x 32 k) transposed into sA[k][m]
#pragma unroll
        for (int l = 0; l < 2; ++l) {
            int f  = tid + l * 256;
            int r  = f >> 3;               // row 0..63
            int k4 = (f & 7) << 2;         // k offset 0..28
            float4 v = make_float4(0.f, 0.f, 0.f, 0.f);
            int gr = row0 + r;
            if (gr < M) v = *(const float4*)&A[(size_t)gr * lda + kb + k4];
            sA[k4 + 0][r] = v.x; sA[k4 + 1][r] = v.y;
            sA[k4 + 2][r] = v.z; sA[k4 + 3][r] = v.w;
        }
        // stage B (32 k-rows x 64 cols) as-is
#pragma unroll
        for (int l = 0; l < 2; ++l) {
            int f  = tid + l * 256;
            int kr = f >> 4;
            int c4 = (f & 15) << 2;
            *(float4*)&sB[kr][c4] = *(const float4*)&B[(size_t)(kb + kr) * N + col0 + c4];
        }
        __syncthreads();
#pragma unroll
        for (int k = 0; k < 32; ++k) {
            float4 a = *(const float4*)&sA[k][ty4];   // one b128: rows ty4..ty4+3
            float4 b = *(const float4*)&sB[k][tx4];
            acc[0][0] = fmaf(a.x, b.x, acc[0][0]); acc[0][1] = fmaf(a.x, b.y, acc[0][1]);
            acc[0][2] = fmaf(a.x, b.z, acc[0][2]); acc[0][3] = fmaf(a.x, b.w, acc[0][3]);
            acc[1][0] = fmaf(a.y, b.x, acc[1][0]); acc[1][1] = fmaf(a.y, b.y, acc[1][1]);
            acc[1][2] = fmaf(a.y, b.z, acc[1][2]); acc[1][3] = fmaf(a.y, b.w, acc[1][3]);
            acc[2][0] = fmaf(a.z, b.x, acc[2][0]); acc[2][1] = fmaf(a.z, b.y, acc[2][1]);
            acc[2][2] = fmaf(a.z, b.z, acc[2][2]); acc[2][3] = fmaf(a.z, b.w, acc[2][3]);
            acc[3][0] = fmaf(a.w, b.x, acc[3][0]); acc[3][1] = fmaf(a.w, b.y, acc[3][1]);
            acc[3][2] = fmaf(a.w, b.z, acc[3][2]); acc[3][3] = fmaf(a.w, b.w, acc[3][3]);
        }
        __syncthreads();
    }

    float4 bv = make_float4(0.f, 0.f, 0.f, 0.f);
    if (bias) bv = *(const float4*)&bias[col0 + tx4];
#pragma unroll
    for (int i = 0; i < 4; ++i) {
        int gr = row0 + ty4 + i;
        if (gr < M) {
            float4 v;
            v.x = acc[i][0] + bv.x; v.y = acc[i][1] + bv.y;
            v.z = acc[i][2] + bv.z; v.w = acc[i][3] + bv.w;
            if (RELU) {
                v.x = fmaxf(v.x, 0.f); v.y = fmaxf(v.y, 0.f);
                v.z = fmaxf(v.z, 0.f); v.w = fmaxf(v.w, 0.f);
            }
            *(float4*)&C[(size_t)gr * N + col0 + tx4] = v;
        }
    }
}

extern "C" void kernel_launch(void* const* d_in, const int* in_sizes, int n_in,
                              void* d_out, int out_size, void* d_ws, size_t ws_size,
                              hipStream_t stream) {
    const float* x     = (const float*)d_in[0];
    const int*   edges = (const int*)d_in[1];
    const float* Wb    = (const float*)d_in[2];
    const float* bb    = (const float*)d_in[3];
    const float* Ws1   = (const float*)d_in[4];
    const float* bs1   = (const float*)d_in[5];
    const float* Ws2   = (const float*)d_in[6];
    const float* bs2   = (const float*)d_in[7];
    const float* Ww1   = (const float*)d_in[8];
    const float* bw1   = (const float*)d_in[9];
    const float* Ww2   = (const float*)d_in[10];
    const float* bw2   = (const float*)d_in[11];

    const int N = in_sizes[0] / 640;   // 50000
    const int E = in_sizes[1] / 2;     // 1600000

    float* out_xs = (float*)d_out;
    float* out_xw = out_xs + (size_t)N * 640;

    // workspace layout (all 256B-aligned)
    const size_t NP = ((size_t)N + 64) & ~63ULL;   // padded count
    char* w = (char*)d_ws;
    float* dinv      = (float*)w;              w += NP * 4;
    int*   cnt       = (int*)w;                w += NP * 4;
    int*   row_start = (int*)w;                w += (NP + 64) * 4;
    int*   cursor    = (int*)w;                w += NP * 4;
    int2*  csr       = (int2*)w;               w += ((size_t)E + 64) * 8;
    float* Wcat      = (float*)w;              w += 8192 * 4;
    float* bcat      = (float*)w;              w += 256 * 4;
    size_t nf = (size_t)N * 64;
    float* B0 = (float*)w;                     w += nf * 4;
    float* B1 = (float*)w;                     w += nf * 4;
    float* B2 = (float*)w;                     w += nf * 4;
    float* Bcat = (float*)w;                   w += (size_t)N * 128 * 4;  // pre-agg 128-wide
    float* B128 = (float*)w;                   w += (size_t)N * 128 * 4;  // post-agg 128-wide

    const dim3 blk(256);
    const int nBlkN   = (N + 255) / 256;
    const int nBlkN1  = (N + 256) / 256;       // covers i == N
    const int nBlkE   = (E + 255) / 256;
    const int nScanB  = (N + 1023) / 1024;
    const int rowT    = (N + 63) / 64;
    const int gatherB = (N + 3) / 4;           // 4 waves per block, 1 wave/node

    // --- CSR build + dinv (coef folded into CSR record) ---
    zero_int_kernel<<<nBlkN, blk, 0, stream>>>(cnt, N);
    hist_kernel<<<nBlkE, blk, 0, stream>>>(edges, cnt, E);
    scan_block_kernel<<<nScanB, 1024, 0, stream>>>(cnt, row_start, cursor /*tmp blocksum*/, dinv, N);
    scan_partials_kernel<<<1, 64, 0, stream>>>(cursor, nScanB);
    scan_finalize_kernel<<<nBlkN1, blk, 0, stream>>>(row_start, cursor, cnt /*reuse as cursor*/, N, E);
    build_csr_kernel<<<nBlkE, blk, 0, stream>>>(edges, cnt, csr, dinv, E);

    // --- concat [Ws1|Ww1], [bs1|bw1] (tiny) ---
    concat_w_kernel<<<16, blk, 0, stream>>>(Ws1, Ww1, bs1, bw1, Wcat, bcat);

    // --- G1: hb = x @ Wb (bias folded into A2's read transform) ---
    gemm_kernel<false><<<dim3(rowT, 1), blk, 0, stream>>>(x, Wb, nullptr, B0, N, 64, 640, 640);

    // --- A1: ab = S(hb) ---
    agg64_kernel<false, false><<<gatherB, blk, 0, stream>>>(B0, nullptr, row_start, csr, dinv, B1, N);

    // --- A2: t1 = S(relu(ab + bb)) ---
    agg64_kernel<true, true><<<gatherB, blk, 0, stream>>>(B1, bb, row_start, csr, dinv, B2, N);

    // --- merged branch heads: Bcat = relu(t1 @ [Ws1|Ww1] + [bs1|bw1]) ---
    gemm_kernel<true><<<dim3(rowT, 2), blk, 0, stream>>>(B2, Wcat, bcat, Bcat, N, 128, 64, 64);

    // --- A3+A4 merged: B128 = S(Bcat), one traversal for both branches ---
    agg128_kernel<<<gatherB, blk, 0, stream>>>(Bcat, row_start, csr, dinv, B128, N);

    // --- epilogues: slice the two halves via lda=128 ---
    gemm_kernel<true><<<dim3(rowT, 10), blk, 0, stream>>>(B128,      Ws2, bs2, out_xs, N, 640, 64, 128);
    gemm_kernel<true><<<dim3(rowT, 10), blk, 0, stream>>>(B128 + 64, Ww2, bw2, out_xw, N, 640, 64, 128);
}